// Round 7
// baseline (226.367 us; speedup 1.0000x reference)
//
#include <hip/hip_runtime.h>
#include <hip/hip_bf16.h>
#include <stdint.h>

// B=2, S=2048, D=1024, H=16, HD=64. Inputs fp32, d_out fp32 (resolved r1-r3).
// canon fp32->bf16 (+ mask*log2e -> bf16 stashed in d_out) -> QKV GEMM
// (Q pre-scaled by 0.125*log2e; V transposed [B,H,HD,S]) -> flash attn
// (32x32 MFMA, kv-split 2-way, no-max exp2 softmax) -> out-proj GEMM fp32.
// r12: mask staged via global_load_lds (attn 104->89us).
// r13: XCD decode + mask bf16 in d_out + 40KB LDS/4 blk-CU (89->69us).
// r14: permlane32_swap P-exchange + b-partitioned XCD decode (69->59us).
// r15: GEMM K-loop rebuilt on the attn-proven async schedule — double-buffered
// LDS (2x16KB), ONE __syncthreads per K-step (its implicit vmcnt(0) is the
// drain), stage(k+1) issued after the barrier so it overlaps compute(k).
// Old structure had ZERO overlap (stage -> immediate drain -> compute).
#define Bb 2
#define Ss 2048
#define Dd 1024
#define Hh 16
#define HD 64

typedef __attribute__((ext_vector_type(8))) __bf16 bf16x8;
typedef __attribute__((ext_vector_type(4))) __bf16 bf16x4;
typedef __attribute__((ext_vector_type(2))) __bf16 bf16x2;
typedef __attribute__((ext_vector_type(4))) float f32x4;
typedef __attribute__((ext_vector_type(16))) float f32x16;

#define LOG2E 1.44269504088896f
#define SCL2 (0.125f * LOG2E)

// ---- workspace layout (bf16 elements) --------------------------------------
#define HS_N   (Bb * Ss * Dd)
#define W_N    (Dd * Dd)
#define B_N    (Dd)
#define MS_N   ((long)Bb * Ss * Ss)
#define CAN_HS 0
#define CAN_WQ (CAN_HS + HS_N)
#define CAN_BQ (CAN_WQ + W_N)
#define CAN_WK (CAN_BQ + B_N)
#define CAN_BK (CAN_WK + W_N)
#define CAN_WV (CAN_BK + B_N)
#define CAN_BV (CAN_WV + W_N)
#define CAN_WO (CAN_BV + B_N)
#define CAN_BO (CAN_WO + W_N)
#define CAN_END (CAN_BO + B_N)
#define TSZ    (Bb * Hh * Ss * HD)
#define WS_ELEMS (CAN_END + 4 * TSZ)
#define WS_NEED ((size_t)WS_ELEMS * 2)

__device__ __forceinline__ void gl_lds16(const __bf16* g, __bf16* l) {
  __builtin_amdgcn_global_load_lds(
      (const __attribute__((address_space(1))) void*)g,
      (__attribute__((address_space(3))) void*)l,
      16, 0, 0);
}

__device__ __forceinline__ void cfence() { asm volatile("" ::: "memory"); }

// fp32 -> bf16 canonicalization (segment table; r4 postmortem).
// r13: also emits mask*log2e as bf16 into mout (aliased to d_out).
__global__ void canon_kernel(const float* hs, const float* Wq, const float* bq,
                             const float* Wk, const float* bk, const float* Wv,
                             const float* bv, const float* Wo, const float* bo,
                             __bf16* __restrict__ dst,
                             const float* __restrict__ Mf,
                             __bf16* __restrict__ mout) {
  const float* srcs[9] = {hs, Wq, bq, Wk, bk, Wv, bv, Wo, bo};
  const long starts[10] = {CAN_HS, CAN_WQ, CAN_BQ, CAN_WK, CAN_BK,
                           CAN_WV, CAN_BV, CAN_WO, CAN_BO, CAN_END};
  const long nA = CAN_END / 8;
  const long nTot = nA + MS_N / 8;
  for (long c = blockIdx.x * blockDim.x + threadIdx.x; c < nTot;
       c += (long)gridDim.x * blockDim.x) {
    if (c < nA) {
      const long i = c * 8;
      int seg = 0;
#pragma unroll
      for (int t = 1; t < 9; t++) seg += (i >= starts[t]) ? 1 : 0;
      const float* s = srcs[seg] + (i - starts[seg]);
      bf16x8 v;
#pragma unroll
      for (int e = 0; e < 8; e++) v[e] = (__bf16)s[e];
      *(bf16x8*)(dst + i) = v;
    } else {
      const long i = (c - nA) * 8;
      const float* s = Mf + i;
      bf16x8 v;
#pragma unroll
      for (int e = 0; e < 8; e++) v[e] = (__bf16)(s[e] * LOG2E);
      *(bf16x8*)(mout + i) = v;
    }
  }
}

// ---------------------------------------------------------------------------
// GEMM: C[4096, 1024(x3)] = A @ W^T + bias (bf16 in).
// r15: async double-buffered K-loop (attn-proven schedule):
//   prologue stage(0); per kt: __syncthreads (implicit vmcnt(0) drains
//   stage(kt)) -> issue stage(kt+1) into buf^1 -> ds_read frags + MFMA on
//   buf. One barrier per K-step; staging has the whole compute phase to land.
// Safety: all waves' frag reads of buf^1 (iteration kt-1) are in registers
// before they reach barrier(kt) (compiler lgkmcnt before MFMA), so the
// stage(kt+1) DMA — which cannot start until every wave passes barrier(kt) —
// never races readers.
// ---------------------------------------------------------------------------
template <int MODE, typename OutT>
__global__ __launch_bounds__(256, 2) void gemm_bt(
    const __bf16* __restrict__ A,
    const __bf16* __restrict__ W0, const __bf16* __restrict__ W1,
    const __bf16* __restrict__ W2,
    const __bf16* __restrict__ b0, const __bf16* __restrict__ b1,
    const __bf16* __restrict__ b2,
    OutT* __restrict__ O0, OutT* __restrict__ O1, OutT* __restrict__ O2) {
  __shared__ __align__(16) __bf16 sA[2][128 * 32];
  __shared__ __align__(16) __bf16 sB[2][128 * 32];
  const int tid = threadIdx.x;
  const int lane = tid & 63;
  const int wid = tid >> 6;
  const int quad = lane >> 4;
  const int l15 = lane & 15;
  const int mBlock = blockIdx.x * 128;

  const __bf16* W;
  const __bf16* bias;
  OutT* Out;
  int nBlock, which = 0;
  if (MODE == 0) {
    which = blockIdx.y >> 3;  // 0:Q 1:K 2:V
    nBlock = (blockIdx.y & 7) * 128;
    W = which == 0 ? W0 : (which == 1 ? W1 : W2);
    bias = which == 0 ? b0 : (which == 1 ? b1 : b2);
    Out = which == 0 ? O0 : (which == 1 ? O1 : O2);
  } else {
    nBlock = blockIdx.y * 128;
    W = W0;
    bias = b0;
    Out = O0;
  }

  const int waveM = (wid >> 1) * 64;
  const int waveN = (wid & 1) * 64;

  f32x4 acc[4][4] = {};

  const int c1 = wid * 64 + lane;
  const int c2 = c1 + 256;
  const __bf16* Ar1 = A + (mBlock + (c1 >> 2)) * Dd + (c1 & 3) * 8;
  const __bf16* Ar2 = A + (mBlock + (c2 >> 2)) * Dd + (c2 & 3) * 8;
  const __bf16* Wr1 = W + (nBlock + (c1 >> 2)) * Dd + (c1 & 3) * 8;
  const __bf16* Wr2 = W + (nBlock + (c2 >> 2)) * Dd + (c2 & 3) * 8;
  const int d1 = (wid * 64) * 8;
  const int d2 = (wid * 64 + 256) * 8;

#define GSTAGE(BI, K0)                                                        \
  {                                                                           \
    gl_lds16(Ar1 + (K0), sA[BI] + d1);                                        \
    gl_lds16(Ar2 + (K0), sA[BI] + d2);                                        \
    gl_lds16(Wr1 + (K0), sB[BI] + d1);                                        \
    gl_lds16(Wr2 + (K0), sB[BI] + d2);                                        \
  }

  GSTAGE(0, 0);  // prologue: tile 0 in flight

#pragma unroll 2
  for (int kt = 0; kt < 32; ++kt) {
    const int bufc = kt & 1;
    __syncthreads();  // implicit s_waitcnt vmcnt(0) = drain stage(kt); barrier
    if (kt < 31) {
      GSTAGE(bufc ^ 1, (kt + 1) * 32);  // overlaps the whole compute phase
    }

    bf16x8 aF[4], bF[4];
#pragma unroll
    for (int mi = 0; mi < 4; mi++)
      aF[mi] =
          *(const bf16x8*)(sA[bufc] + (waveM + mi * 16 + l15) * 32 + quad * 8);
#pragma unroll
    for (int ni = 0; ni < 4; ni++)
      bF[ni] =
          *(const bf16x8*)(sB[bufc] + (waveN + ni * 16 + l15) * 32 + quad * 8);
#pragma unroll
    for (int mi = 0; mi < 4; mi++)
#pragma unroll
      for (int ni = 0; ni < 4; ni++)
        acc[mi][ni] = __builtin_amdgcn_mfma_f32_16x16x32_bf16(
            aF[mi], bF[ni], acc[mi][ni], 0, 0, 0);
  }

  // C/D layout: col = lane&15, row = quad*4 + r.
#pragma unroll
  for (int ni = 0; ni < 4; ni++) {
    const int ng = nBlock + waveN + ni * 16 + l15;
    const float bv = (float)bias[ng];
#pragma unroll
    for (int mi = 0; mi < 4; mi++) {
      const int mg0 = mBlock + waveM + mi * 16 + quad * 4;
      if (MODE == 0 && which == 2) {
        const int b = mg0 >> 11, s0 = mg0 & 2047;
        const int h = ng >> 6, hd = ng & 63;
        bf16x4 pk;
#pragma unroll
        for (int r = 0; r < 4; r++) pk[r] = (__bf16)(acc[mi][ni][r] + bv);
        *(bf16x4*)((__bf16*)Out + (((b * Hh + h) * HD + hd) * Ss) + s0) = pk;
      } else {
#pragma unroll
        for (int r = 0; r < 4; r++) {
          float v = acc[mi][ni][r] + bv;
          const int m = mg0 + r;
          if (MODE == 0) {
            if (which == 0) v *= SCL2;  // fold softmax scale+log2e into Q
            const int b = m >> 11, s = m & 2047;
            const int h = ng >> 6, hd = ng & 63;
            Out[(((b * Hh + h) * Ss + s) * HD) + hd] = (OutT)v;
          } else {
            Out[m * Dd + ng] = (OutT)v;
          }
        }
      }
    }
  }
}

// ---------------------------------------------------------------------------
// Flash attention r14 (unchanged in r15): 32x32 MFMA, kv-split 2-way, no-max
// softmax. Grid 1024 flat; b-partitioned XCD decode. Per iter:
// vmcnt(0) -> barrier A -> K/V stage(i+1) -> mask read -> lgkmcnt(0)
// -> barrier B -> mask stage(i+1) -> compute(i).
// P-exchange: v_permlane32_swap_b32 (vdst.hi <-> src.lo, r14-verified).
// ---------------------------------------------------------------------------
__global__ __launch_bounds__(256, 4) void attn_fused(
    const __bf16* __restrict__ Qg, const __bf16* __restrict__ Kg,
    const __bf16* __restrict__ Vt, const __bf16* __restrict__ Mbf,
    __bf16* __restrict__ Og) {
  __shared__ __align__(16) union {
    struct {
      __bf16 kv[2][8192];  // [buffer][K 4096 | V 4096]
      __bf16 mk[4096];     // mask tile 64q x 64kv bf16 (8 chunks/row)
    } s;
    struct {
      float O[2][64][32];  // [qg][hd][q] kv-half-1 partial
      float L[2][32];
    } m;
  } sh;

  const int tid = threadIdx.x;
  const int lane = tid & 63;
  const int wid = tid >> 6;
  const int qg = wid & 1;
  const int kvh = wid >> 1;
  const int l31 = lane & 31;
  const int hi = lane >> 5;

  // b-partitioned XCD-bijective decode (id&7 = XCD under round-robin).
  const int id = blockIdx.x;
  const int j = id >> 3;                   // [0,128)
  const int bh = (id & 7) * 4 + (j >> 5);  // XCD x owns bh {4x..4x+3}
  const int qb0 = (j & 31) * 64;           // q-block
  const int b = bh >> 4;
  const int h = bh & 15;
  const int qw = qb0 + qg * 32 + l31;      // this lane's q row

  const __bf16* Qp = Qg + (size_t)bh * Ss * HD;
  const __bf16* Kp = Kg + (size_t)bh * Ss * HD;
  const __bf16* Vp = Vt + (size_t)bh * HD * Ss;  // [hd][S]
  const __bf16* Mb = Mbf + (size_t)b * Ss * Ss;  // bf16, pre-scaled log2e

  // Q B-fragments in registers (B[k=hd][n=q]; lane: hd = 16k + 8hi + j).
  bf16x8 qf[4];
#pragma unroll
  for (int k = 0; k < 4; k++)
    qf[k] = *(const bf16x8*)(Qp + (size_t)qw * HD + k * 16 + hi * 8);

  const int cA = tid, cB = 256 + tid;
  // K/V staging (r9-proven): linear LDS dest, source carries the slot
  // swizzle ((row>>1)&3).
#define STAGE_KV(BI, KVS)                                                     \
  {                                                                           \
    const int rwA = (cA & 255) >> 2, rwB = (cB & 255) >> 2;                   \
    const int slA = (cA & 3) ^ ((rwA >> 1) & 3);                              \
    const int slB = (cB & 3) ^ ((rwB >> 1) & 3);                              \
    __bf16* kb = sh.s.kv[BI];                                                 \
    gl_lds16(Kp + ((KVS) + rwA) * HD + (cA >> 8) * 32 + slA * 8, kb + cA * 8);\
    gl_lds16(Kp + ((KVS) + rwB) * HD + (cB >> 8) * 32 + slB * 8, kb + cB * 8);\
    __bf16* vb = sh.s.kv[BI] + 4096;                                          \
    gl_lds16(Vp + (size_t)rwA * Ss + (KVS) + (cA >> 8) * 32 + slA * 8,        \
             vb + cA * 8);                                                    \
    gl_lds16(Vp + (size_t)rwB * Ss + (KVS) + (cB >> 8) * 32 + slB * 8,        \
             vb + cB * 8);                                                    \
  }

  // Mask staging: 512 16B-chunks (8 bf16 each), 2 per thread. Chunk c lands
  // linearly at slot c = row mq (c>>3) x phys8 (c&7); source fetches logical
  // chunk l8 = (c&7) ^ (mq&7) so the read-side XOR is an involution.
#define STAGE_M(KVS)                                                          \
  {                                                                           \
    _Pragma("unroll")                                                         \
    for (int rr = 0; rr < 2; rr++) {                                          \
      const int c = tid + rr * 256;                                           \
      const int mq = c >> 3;                                                  \
      const int l8 = (c & 7) ^ (mq & 7);                                      \
      gl_lds16(Mb + (size_t)(qb0 + mq) * Ss + (KVS) + l8 * 8,                 \
               sh.s.mk + c * 8);                                              \
    }                                                                         \
  }

  f32x16 o[2] = {};  // O^T partials: row=hd (C-layout), col=q
  f32x4 lacc = {0.f, 0.f, 0.f, 0.f};

  const int rsw = (l31 >> 1) & 3;  // K/V read-side slot XOR (row>>1)&3

  // Prologue: tile 0 K/V + mask(0) staged.
  STAGE_KV(0, 0);
  STAGE_M(0);

  for (int it = 0; it < 32; ++it) {
    const int bufc = it & 1;
    cfence();
    asm volatile("s_waitcnt vmcnt(0)" ::: "memory");  // drain stage(it)
    cfence();
    __builtin_amdgcn_s_barrier();  // A: tile-i K/V + mask visible
    cfence();
    if (it < 31) {
      STAGE_KV(bufc ^ 1, (it + 1) * 64);  // K/V prefetch overlaps everything
      cfence();
    }

    // Read mask(i) tile from LDS: lane wants row mq = qg*32+l31,
    // kv = 32kvh + 8g + 4hi + r -> logical chunk l8 = 4kvh + g,
    // phys8 = l8 ^ (mq&7), within-chunk offset 4hi.
    bf16x4 mcv[4];
    const int mq = qg * 32 + l31;
#pragma unroll
    for (int g = 0; g < 4; g++) {
      const int p8 = (4 * kvh + g) ^ (l31 & 7);
      mcv[g] = *(const bf16x4*)(sh.s.mk + mq * 64 + p8 * 8 + 4 * hi);
    }
    cfence();
    asm volatile("s_waitcnt lgkmcnt(0)" ::: "memory");  // mask reads done
    cfence();
    __builtin_amdgcn_s_barrier();  // B: all waves consumed mask(i)
    cfence();
    if (it < 31) {
      STAGE_M((it + 1) * 64);  // safe to overwrite mask tile now
      cfence();
    }

    // S^T = K Q^T with C-init = mask (already *log2e; layout: reg g*4+r <->
    // kv = 8g+4hi+r, col q = l31).
    f32x16 sacc;
#pragma unroll
    for (int g = 0; g < 4; g++)
#pragma unroll
      for (int r = 0; r < 4; r++) sacc[g * 4 + r] = (float)mcv[g][r];
    __builtin_amdgcn_s_setprio(1);
#pragma unroll
    for (int k = 0; k < 4; k++) {
      const int ps = (((k & 1) << 1) | hi) ^ rsw;  // swizzled slot
      bf16x8 kf = *(const bf16x8*)(sh.s.kv[bufc] +
                                   ((k >> 1) * 64 + kvh * 32 + l31) * 32 +
                                   ps * 8);
      sacc = __builtin_amdgcn_mfma_f32_32x32x16_bf16(kf, qf[k], sacc, 0, 0, 0);
    }
    __builtin_amdgcn_s_setprio(0);

    // p = exp2(s); row-sum into lacc.
    f32x4 sv[4];
#pragma unroll
    for (int g = 0; g < 4; g++)
#pragma unroll
      for (int r = 0; r < 4; r++)
        sv[g][r] = __builtin_amdgcn_exp2f(sacc[g * 4 + r]);
    lacc += (sv[0] + sv[1]) + (sv[2] + sv[3]);

    // P^T B-fragments via v_permlane32_swap_b32 (vdst.hi <-> src.lo):
    //   (a',b') = swap(a = pk[2ks].w, b = pk[2ks+1].w)
    // -> pf[ks] = {a'0, a'1, b'0, b'1} valid for BOTH lane halves.
    union pu { bf16x4 v; uint32_t w[2]; };
    pu pk[4];
#pragma unroll
    for (int g = 0; g < 4; g++)
#pragma unroll
      for (int r = 0; r < 4; r++) pk[g].v[r] = (__bf16)sv[g][r];
    union PF { bf16x8 v; uint32_t u[4]; } pf[2];
#pragma unroll
    for (int ks = 0; ks < 2; ks++) {
      uint32_t a0 = pk[2 * ks].w[0], b0 = pk[2 * ks + 1].w[0];
      uint32_t a1 = pk[2 * ks].w[1], b1 = pk[2 * ks + 1].w[1];
      asm volatile("s_nop 1\n\tv_permlane32_swap_b32 %0, %1"
                   : "+v"(a0), "+v"(b0));
      asm volatile("s_nop 1\n\tv_permlane32_swap_b32 %0, %1"
                   : "+v"(a1), "+v"(b1));
      pf[ks].u[0] = a0;
      pf[ks].u[1] = a1;
      pf[ks].u[2] = b0;
      pf[ks].u[3] = b1;
    }

    // O^T += V^T P^T (contraction over wave's kv 32: 2 ksteps).
    __builtin_amdgcn_s_setprio(1);
#pragma unroll
    for (int k = 0; k < 2; k++)
#pragma unroll
      for (int hb = 0; hb < 2; hb++) {
        const int ps = ((k << 1) | hi) ^ rsw;  // swizzled slot
        bf16x8 vf = *(const bf16x8*)(sh.s.kv[bufc] + 4096 +
                                     (kvh * 64 + hb * 32 + l31) * 32 +
                                     ps * 8);
        o[hb] = __builtin_amdgcn_mfma_f32_32x32x16_bf16(vf, pf[k].v, o[hb],
                                                        0, 0, 0);
      }
    __builtin_amdgcn_s_setprio(0);
  }

  float l = lacc[0] + lacc[1] + lacc[2] + lacc[3];
  l += __shfl_xor(l, 32);

  __syncthreads();  // all compute done; union switches to merge arrays
  // Merge kv-halves (plain add — no-max softmax has no rescale factor).
  if (kvh == 1) {
#pragma unroll
    for (int hb = 0; hb < 2; hb++)
#pragma unroll
      for (int r = 0; r < 16; r++) {
        const int hd = hb * 32 + (r & 3) + 8 * (r >> 2) + 4 * hi;
        sh.m.O[qg][hd][l31] = o[hb][r];
      }
    if (hi == 0) sh.m.L[qg][l31] = l;
  }
  __syncthreads();
  if (kvh == 0) {
#pragma unroll
    for (int hb = 0; hb < 2; hb++)
#pragma unroll
      for (int r = 0; r < 16; r++) {
        const int hd = hb * 32 + (r & 3) + 8 * (r >> 2) + 4 * hi;
        o[hb][r] += sh.m.O[qg][hd][l31];
      }
    l += sh.m.L[qg][l31];
    const float inv = 1.0f / l;
    __bf16* Ow = Og + (((size_t)b * Ss + qw) * Hh + h) * HD;
#pragma unroll
    for (int hb = 0; hb < 2; hb++)
#pragma unroll
      for (int g = 0; g < 4; g++) {
        const int hd = hb * 32 + g * 8 + 4 * hi;
        bf16x2 w0, w1;
        w0[0] = (__bf16)(o[hb][g * 4 + 0] * inv);
        w0[1] = (__bf16)(o[hb][g * 4 + 1] * inv);
        w1[0] = (__bf16)(o[hb][g * 4 + 2] * inv);
        w1[1] = (__bf16)(o[hb][g * 4 + 3] * inv);
        *(bf16x2*)(Ow + hd) = w0;
        *(bf16x2*)(Ow + hd + 2) = w1;
      }
  }
}

// ---------------------------------------------------------------------------
extern "C" void kernel_launch(void* const* d_in, const int* in_sizes, int n_in,
                              void* d_out, int out_size, void* d_ws,
                              size_t ws_size, hipStream_t stream) {
  if (ws_size < WS_NEED) return;

  __bf16* ws = (__bf16*)d_ws;
  const __bf16* hsC = ws + CAN_HS;
  const __bf16* WqC = ws + CAN_WQ;
  const __bf16* bqC = ws + CAN_BQ;
  const __bf16* WkC = ws + CAN_WK;
  const __bf16* bkC = ws + CAN_BK;
  const __bf16* WvC = ws + CAN_WV;
  const __bf16* bvC = ws + CAN_BV;
  const __bf16* WoC = ws + CAN_WO;
  const __bf16* boC = ws + CAN_BO;
  __bf16* Q = ws + CAN_END;
  __bf16* K = Q + TSZ;
  __bf16* V = K + TSZ;  // transposed layout [B,H,HD,S]
  __bf16* AW = V + TSZ;
  float* out = (float*)d_out;
  // bf16 mask (pre-scaled by log2e) lives in d_out until out-proj overwrites
  // it: B*S*S bf16 = 16.78MB = B*S*D fp32 exactly.
  __bf16* Mbf = (__bf16*)d_out;

  canon_kernel<<<2048, 256, 0, stream>>>(
      (const float*)d_in[0], (const float*)d_in[2], (const float*)d_in[3],
      (const float*)d_in[4], (const float*)d_in[5], (const float*)d_in[6],
      (const float*)d_in[7], (const float*)d_in[8], (const float*)d_in[9], ws,
      (const float*)d_in[1], Mbf);
  gemm_bt<0, __bf16><<<dim3(32, 24), 256, 0, stream>>>(
      hsC, WqC, WkC, WvC, bqC, bkC, bvC, Q, K, V);
  attn_fused<<<dim3(1024), 256, 0, stream>>>(Q, K, V, Mbf, AW);
  gemm_bt<1, float><<<dim3(32, 8), 256, 0, stream>>>(
      AW, WoC, WoC, WoC, boC, boC, boC, out, out, out);
}

// Round 8
// 222.628 us; speedup vs baseline: 1.0168x; 1.0168x over previous
//
#include <hip/hip_runtime.h>
#include <hip/hip_bf16.h>
#include <stdint.h>

// B=2, S=2048, D=1024, H=16, HD=64. Inputs fp32, d_out fp32 (resolved r1-r3).
// canon fp32->bf16 -> QKV GEMM (+ mask*log2e->bf16 convert fused in as 8
// extra grid.y planes — overlaps the compute-bound GEMM; mask bf16 lives in
// d_out until out-proj overwrites it) -> flash attn (32x32 MFMA, kv-split
// 2-way, no-max exp2 softmax) -> out-proj GEMM fp32 (128x64 tiles, 512
// blocks = 2/CU).
// r12: mask staged via global_load_lds (attn 104->89us).
// r13: XCD decode + mask bf16 in d_out + 40KB LDS/4 blk-CU (89->69us).
// r14: permlane32_swap P-exchange + b-partitioned XCD decode (69->59us).
// r15: GEMM dbuf — NEUTRAL (matches learn_hip m99/m100; drain is structural).
// r16: (a) mask-canon moved INTO QKV GEMM as early-exit blocks (overlap);
// (b) out-proj retiled 128x64, grid 32x16 -> 2 blocks/CU.
#define Bb 2
#define Ss 2048
#define Dd 1024
#define Hh 16
#define HD 64

typedef __attribute__((ext_vector_type(8))) __bf16 bf16x8;
typedef __attribute__((ext_vector_type(4))) __bf16 bf16x4;
typedef __attribute__((ext_vector_type(2))) __bf16 bf16x2;
typedef __attribute__((ext_vector_type(4))) float f32x4;
typedef __attribute__((ext_vector_type(16))) float f32x16;

#define LOG2E 1.44269504088896f
#define SCL2 (0.125f * LOG2E)

// ---- workspace layout (bf16 elements) --------------------------------------
#define HS_N   (Bb * Ss * Dd)
#define W_N    (Dd * Dd)
#define B_N    (Dd)
#define MS_N   ((long)Bb * Ss * Ss)
#define CAN_HS 0
#define CAN_WQ (CAN_HS + HS_N)
#define CAN_BQ (CAN_WQ + W_N)
#define CAN_WK (CAN_BQ + B_N)
#define CAN_BK (CAN_WK + W_N)
#define CAN_WV (CAN_BK + B_N)
#define CAN_BV (CAN_WV + W_N)
#define CAN_WO (CAN_BV + B_N)
#define CAN_BO (CAN_WO + W_N)
#define CAN_END (CAN_BO + B_N)
#define TSZ    (Bb * Hh * Ss * HD)
#define WS_ELEMS (CAN_END + 4 * TSZ)
#define WS_NEED ((size_t)WS_ELEMS * 2)

__device__ __forceinline__ void gl_lds16(const __bf16* g, __bf16* l) {
  __builtin_amdgcn_global_load_lds(
      (const __attribute__((address_space(1))) void*)g,
      (__attribute__((address_space(3))) void*)l,
      16, 0, 0);
}

__device__ __forceinline__ void cfence() { asm volatile("" ::: "memory"); }

// fp32 -> bf16 canonicalization of hs + weights + biases only (mask handled
// inside the QKV GEMM launch, overlapped with compute).
__global__ void canon_kernel(const float* hs, const float* Wq, const float* bq,
                             const float* Wk, const float* bk, const float* Wv,
                             const float* bv, const float* Wo, const float* bo,
                             __bf16* __restrict__ dst) {
  const float* srcs[9] = {hs, Wq, bq, Wk, bk, Wv, bv, Wo, bo};
  const long starts[10] = {CAN_HS, CAN_WQ, CAN_BQ, CAN_WK, CAN_BK,
                           CAN_WV, CAN_BV, CAN_WO, CAN_BO, CAN_END};
  const long nA = CAN_END / 8;
  for (long c = blockIdx.x * blockDim.x + threadIdx.x; c < nA;
       c += (long)gridDim.x * blockDim.x) {
    const long i = c * 8;
    int seg = 0;
#pragma unroll
    for (int t = 1; t < 9; t++) seg += (i >= starts[t]) ? 1 : 0;
    const float* s = srcs[seg] + (i - starts[seg]);
    bf16x8 v;
#pragma unroll
    for (int e = 0; e < 8; e++) v[e] = (__bf16)s[e];
    *(bf16x8*)(dst + i) = v;
  }
}

// ---------------------------------------------------------------------------
// GEMM: C = A @ W^T + bias (bf16 in).
// MODE 0 (QKV): 128x128 tiles, grid (32, 24 GEMM + 8 mask-canon planes).
//   Blocks with y>=24 early-exit into a grid-stride mask fp32->bf16*log2e
//   convert (memory-bound; overlaps the compute-bound GEMM blocks).
// MODE 1 (out-proj): 128x64 tiles, grid (32,16) = 512 blocks -> 2 blocks/CU.
// K-loop: r15 double-buffered schedule (neutral but harmless).
// ---------------------------------------------------------------------------
template <int MODE, typename OutT>
__global__ __launch_bounds__(256, 2) void gemm_bt(
    const __bf16* __restrict__ A,
    const __bf16* __restrict__ W0, const __bf16* __restrict__ W1,
    const __bf16* __restrict__ W2,
    const __bf16* __restrict__ b0, const __bf16* __restrict__ b1,
    const __bf16* __restrict__ b2,
    OutT* __restrict__ O0, OutT* __restrict__ O1, OutT* __restrict__ O2,
    const float* __restrict__ Mf, __bf16* __restrict__ Mout) {
  constexpr int TN = (MODE == 1) ? 64 : 128;   // N-tile
  constexpr int NACC = TN / 32;                // per-wave 16-col frags
  __shared__ __align__(16) __bf16 sA[2][128 * 32];
  __shared__ __align__(16) __bf16 sB[2][TN * 32];
  const int tid = threadIdx.x;

  if (MODE == 0 && blockIdx.y >= 24) {
    // Fused mask-canon: 256 blocks, grid-stride over 1,048,576 bf16x8 chunks.
    const long nC = MS_N / 8;
    const long c0 = ((long)(blockIdx.y - 24) * 32 + blockIdx.x) * 256 + tid;
    for (long c = c0; c < nC; c += 65536) {
      const float* s = Mf + c * 8;
      bf16x8 v;
#pragma unroll
      for (int e = 0; e < 8; e++) v[e] = (__bf16)(s[e] * LOG2E);
      *(bf16x8*)(Mout + c * 8) = v;
    }
    return;
  }

  const int lane = tid & 63;
  const int wid = tid >> 6;
  const int quad = lane >> 4;
  const int l15 = lane & 15;
  const int mBlock = blockIdx.x * 128;

  const __bf16* W;
  const __bf16* bias;
  OutT* Out;
  int nBlock, which = 0;
  if (MODE == 0) {
    which = blockIdx.y >> 3;  // 0:Q 1:K 2:V
    nBlock = (blockIdx.y & 7) * 128;
    W = which == 0 ? W0 : (which == 1 ? W1 : W2);
    bias = which == 0 ? b0 : (which == 1 ? b1 : b2);
    Out = which == 0 ? O0 : (which == 1 ? O1 : O2);
  } else {
    nBlock = blockIdx.y * TN;
    W = W0;
    bias = b0;
    Out = O0;
  }

  const int waveM = (wid >> 1) * 64;
  const int waveN = (wid & 1) * (TN / 2);

  f32x4 acc[4][NACC] = {};

  const int c1 = wid * 64 + lane;
  const int c2 = c1 + 256;
  const __bf16* Ar1 = A + (mBlock + (c1 >> 2)) * Dd + (c1 & 3) * 8;
  const __bf16* Ar2 = A + (mBlock + (c2 >> 2)) * Dd + (c2 & 3) * 8;
  const __bf16* Wr1 = W + (nBlock + (c1 >> 2)) * Dd + (c1 & 3) * 8;
  const __bf16* Wr2 = W + (nBlock + (c2 >> 2)) * Dd + (c2 & 3) * 8;
  const int d1 = (wid * 64) * 8;
  const int d2 = (wid * 64 + 256) * 8;

#define GSTAGE(BI, K0)                                                        \
  {                                                                           \
    gl_lds16(Ar1 + (K0), sA[BI] + d1);                                        \
    gl_lds16(Ar2 + (K0), sA[BI] + d2);                                        \
    gl_lds16(Wr1 + (K0), sB[BI] + d1);                                        \
    if (MODE == 0) gl_lds16(Wr2 + (K0), sB[BI] + d2);                         \
  }

  GSTAGE(0, 0);  // prologue: tile 0 in flight

#pragma unroll 2
  for (int kt = 0; kt < 32; ++kt) {
    const int bufc = kt & 1;
    __syncthreads();  // implicit s_waitcnt vmcnt(0) = drain stage(kt); barrier
    if (kt < 31) {
      GSTAGE(bufc ^ 1, (kt + 1) * 32);  // overlaps the compute phase
    }

    bf16x8 aF[4], bF[NACC];
#pragma unroll
    for (int mi = 0; mi < 4; mi++)
      aF[mi] =
          *(const bf16x8*)(sA[bufc] + (waveM + mi * 16 + l15) * 32 + quad * 8);
#pragma unroll
    for (int ni = 0; ni < NACC; ni++)
      bF[ni] =
          *(const bf16x8*)(sB[bufc] + (waveN + ni * 16 + l15) * 32 + quad * 8);
#pragma unroll
    for (int mi = 0; mi < 4; mi++)
#pragma unroll
      for (int ni = 0; ni < NACC; ni++)
        acc[mi][ni] = __builtin_amdgcn_mfma_f32_16x16x32_bf16(
            aF[mi], bF[ni], acc[mi][ni], 0, 0, 0);
  }

  // C/D layout: col = lane&15, row = quad*4 + r.
#pragma unroll
  for (int ni = 0; ni < NACC; ni++) {
    const int ng = nBlock + waveN + ni * 16 + l15;
    const float bv = (float)bias[ng];
#pragma unroll
    for (int mi = 0; mi < 4; mi++) {
      const int mg0 = mBlock + waveM + mi * 16 + quad * 4;
      if (MODE == 0 && which == 2) {
        const int b = mg0 >> 11, s0 = mg0 & 2047;
        const int h = ng >> 6, hd = ng & 63;
        bf16x4 pk;
#pragma unroll
        for (int r = 0; r < 4; r++) pk[r] = (__bf16)(acc[mi][ni][r] + bv);
        *(bf16x4*)((__bf16*)Out + (((b * Hh + h) * HD + hd) * Ss) + s0) = pk;
      } else {
#pragma unroll
        for (int r = 0; r < 4; r++) {
          float v = acc[mi][ni][r] + bv;
          const int m = mg0 + r;
          if (MODE == 0) {
            if (which == 0) v *= SCL2;  // fold softmax scale+log2e into Q
            const int b = m >> 11, s = m & 2047;
            const int h = ng >> 6, hd = ng & 63;
            Out[(((b * Hh + h) * Ss + s) * HD) + hd] = (OutT)v;
          } else {
            Out[m * Dd + ng] = (OutT)v;
          }
        }
      }
    }
  }
}

// ---------------------------------------------------------------------------
// Flash attention (r14, unchanged): 32x32 MFMA, kv-split 2-way, no-max
// softmax. Grid 1024 flat; b-partitioned XCD decode. Per iter:
// vmcnt(0) -> barrier A -> K/V stage(i+1) -> mask read -> lgkmcnt(0)
// -> barrier B -> mask stage(i+1) -> compute(i).
// P-exchange: v_permlane32_swap_b32 (vdst.hi <-> src.lo, r14-verified).
// ---------------------------------------------------------------------------
__global__ __launch_bounds__(256, 4) void attn_fused(
    const __bf16* __restrict__ Qg, const __bf16* __restrict__ Kg,
    const __bf16* __restrict__ Vt, const __bf16* __restrict__ Mbf,
    __bf16* __restrict__ Og) {
  __shared__ __align__(16) union {
    struct {
      __bf16 kv[2][8192];  // [buffer][K 4096 | V 4096]
      __bf16 mk[4096];     // mask tile 64q x 64kv bf16 (8 chunks/row)
    } s;
    struct {
      float O[2][64][32];  // [qg][hd][q] kv-half-1 partial
      float L[2][32];
    } m;
  } sh;

  const int tid = threadIdx.x;
  const int lane = tid & 63;
  const int wid = tid >> 6;
  const int qg = wid & 1;
  const int kvh = wid >> 1;
  const int l31 = lane & 31;
  const int hi = lane >> 5;

  // b-partitioned XCD-bijective decode (id&7 = XCD under round-robin).
  const int id = blockIdx.x;
  const int j = id >> 3;                   // [0,128)
  const int bh = (id & 7) * 4 + (j >> 5);  // XCD x owns bh {4x..4x+3}
  const int qb0 = (j & 31) * 64;           // q-block
  const int b = bh >> 4;
  const int h = bh & 15;
  const int qw = qb0 + qg * 32 + l31;      // this lane's q row

  const __bf16* Qp = Qg + (size_t)bh * Ss * HD;
  const __bf16* Kp = Kg + (size_t)bh * Ss * HD;
  const __bf16* Vp = Vt + (size_t)bh * HD * Ss;  // [hd][S]
  const __bf16* Mb = Mbf + (size_t)b * Ss * Ss;  // bf16, pre-scaled log2e

  // Q B-fragments in registers (B[k=hd][n=q]; lane: hd = 16k + 8hi + j).
  bf16x8 qf[4];
#pragma unroll
  for (int k = 0; k < 4; k++)
    qf[k] = *(const bf16x8*)(Qp + (size_t)qw * HD + k * 16 + hi * 8);

  const int cA = tid, cB = 256 + tid;
  // K/V staging (r9-proven): linear LDS dest, source carries the slot
  // swizzle ((row>>1)&3).
#define STAGE_KV(BI, KVS)                                                     \
  {                                                                           \
    const int rwA = (cA & 255) >> 2, rwB = (cB & 255) >> 2;                   \
    const int slA = (cA & 3) ^ ((rwA >> 1) & 3);                              \
    const int slB = (cB & 3) ^ ((rwB >> 1) & 3);                              \
    __bf16* kb = sh.s.kv[BI];                                                 \
    gl_lds16(Kp + ((KVS) + rwA) * HD + (cA >> 8) * 32 + slA * 8, kb + cA * 8);\
    gl_lds16(Kp + ((KVS) + rwB) * HD + (cB >> 8) * 32 + slB * 8, kb + cB * 8);\
    __bf16* vb = sh.s.kv[BI] + 4096;                                          \
    gl_lds16(Vp + (size_t)rwA * Ss + (KVS) + (cA >> 8) * 32 + slA * 8,        \
             vb + cA * 8);                                                    \
    gl_lds16(Vp + (size_t)rwB * Ss + (KVS) + (cB >> 8) * 32 + slB * 8,        \
             vb + cB * 8);                                                    \
  }

  // Mask staging: 512 16B-chunks (8 bf16 each), 2 per thread. Chunk c lands
  // linearly at slot c = row mq (c>>3) x phys8 (c&7); source fetches logical
  // chunk l8 = (c&7) ^ (mq&7) so the read-side XOR is an involution.
#define STAGE_M(KVS)                                                          \
  {                                                                           \
    _Pragma("unroll")                                                         \
    for (int rr = 0; rr < 2; rr++) {                                          \
      const int c = tid + rr * 256;                                           \
      const int mq = c >> 3;                                                  \
      const int l8 = (c & 7) ^ (mq & 7);                                      \
      gl_lds16(Mb + (size_t)(qb0 + mq) * Ss + (KVS) + l8 * 8,                 \
               sh.s.mk + c * 8);                                              \
    }                                                                         \
  }

  f32x16 o[2] = {};  // O^T partials: row=hd (C-layout), col=q
  f32x4 lacc = {0.f, 0.f, 0.f, 0.f};

  const int rsw = (l31 >> 1) & 3;  // K/V read-side slot XOR (row>>1)&3

  // Prologue: tile 0 K/V + mask(0) staged.
  STAGE_KV(0, 0);
  STAGE_M(0);

  for (int it = 0; it < 32; ++it) {
    const int bufc = it & 1;
    cfence();
    asm volatile("s_waitcnt vmcnt(0)" ::: "memory");  // drain stage(it)
    cfence();
    __builtin_amdgcn_s_barrier();  // A: tile-i K/V + mask visible
    cfence();
    if (it < 31) {
      STAGE_KV(bufc ^ 1, (it + 1) * 64);  // K/V prefetch overlaps everything
      cfence();
    }

    // Read mask(i) tile from LDS: lane wants row mq = qg*32+l31,
    // kv = 32kvh + 8g + 4hi + r -> logical chunk l8 = 4kvh + g,
    // phys8 = l8 ^ (mq&7), within-chunk offset 4hi.
    bf16x4 mcv[4];
    const int mq = qg * 32 + l31;
#pragma unroll
    for (int g = 0; g < 4; g++) {
      const int p8 = (4 * kvh + g) ^ (l31 & 7);
      mcv[g] = *(const bf16x4*)(sh.s.mk + mq * 64 + p8 * 8 + 4 * hi);
    }
    cfence();
    asm volatile("s_waitcnt lgkmcnt(0)" ::: "memory");  // mask reads done
    cfence();
    __builtin_amdgcn_s_barrier();  // B: all waves consumed mask(i)
    cfence();
    if (it < 31) {
      STAGE_M((it + 1) * 64);  // safe to overwrite mask tile now
      cfence();
    }

    // S^T = K Q^T with C-init = mask (already *log2e; layout: reg g*4+r <->
    // kv = 8g+4hi+r, col q = l31).
    f32x16 sacc;
#pragma unroll
    for (int g = 0; g < 4; g++)
#pragma unroll
      for (int r = 0; r < 4; r++) sacc[g * 4 + r] = (float)mcv[g][r];
    __builtin_amdgcn_s_setprio(1);
#pragma unroll
    for (int k = 0; k < 4; k++) {
      const int ps = (((k & 1) << 1) | hi) ^ rsw;  // swizzled slot
      bf16x8 kf = *(const bf16x8*)(sh.s.kv[bufc] +
                                   ((k >> 1) * 64 + kvh * 32 + l31) * 32 +
                                   ps * 8);
      sacc = __builtin_amdgcn_mfma_f32_32x32x16_bf16(kf, qf[k], sacc, 0, 0, 0);
    }
    __builtin_amdgcn_s_setprio(0);

    // p = exp2(s); row-sum into lacc.
    f32x4 sv[4];
#pragma unroll
    for (int g = 0; g < 4; g++)
#pragma unroll
      for (int r = 0; r < 4; r++)
        sv[g][r] = __builtin_amdgcn_exp2f(sacc[g * 4 + r]);
    lacc += (sv[0] + sv[1]) + (sv[2] + sv[3]);

    // P^T B-fragments via v_permlane32_swap_b32 (vdst.hi <-> src.lo):
    //   (a',b') = swap(a = pk[2ks].w, b = pk[2ks+1].w)
    // -> pf[ks] = {a'0, a'1, b'0, b'1} valid for BOTH lane halves.
    union pu { bf16x4 v; uint32_t w[2]; };
    pu pk[4];
#pragma unroll
    for (int g = 0; g < 4; g++)
#pragma unroll
      for (int r = 0; r < 4; r++) pk[g].v[r] = (__bf16)sv[g][r];
    union PF { bf16x8 v; uint32_t u[4]; } pf[2];
#pragma unroll
    for (int ks = 0; ks < 2; ks++) {
      uint32_t a0 = pk[2 * ks].w[0], b0 = pk[2 * ks + 1].w[0];
      uint32_t a1 = pk[2 * ks].w[1], b1 = pk[2 * ks + 1].w[1];
      asm volatile("s_nop 1\n\tv_permlane32_swap_b32 %0, %1"
                   : "+v"(a0), "+v"(b0));
      asm volatile("s_nop 1\n\tv_permlane32_swap_b32 %0, %1"
                   : "+v"(a1), "+v"(b1));
      pf[ks].u[0] = a0;
      pf[ks].u[1] = a1;
      pf[ks].u[2] = b0;
      pf[ks].u[3] = b1;
    }

    // O^T += V^T P^T (contraction over wave's kv 32: 2 ksteps).
    __builtin_amdgcn_s_setprio(1);
#pragma unroll
    for (int k = 0; k < 2; k++)
#pragma unroll
      for (int hb = 0; hb < 2; hb++) {
        const int ps = ((k << 1) | hi) ^ rsw;  // swizzled slot
        bf16x8 vf = *(const bf16x8*)(sh.s.kv[bufc] + 4096 +
                                     (kvh * 64 + hb * 32 + l31) * 32 +
                                     ps * 8);
        o[hb] = __builtin_amdgcn_mfma_f32_32x32x16_bf16(vf, pf[k].v, o[hb],
                                                        0, 0, 0);
      }
    __builtin_amdgcn_s_setprio(0);
  }

  float l = lacc[0] + lacc[1] + lacc[2] + lacc[3];
  l += __shfl_xor(l, 32);

  __syncthreads();  // all compute done; union switches to merge arrays
  // Merge kv-halves (plain add — no-max softmax has no rescale factor).
  if (kvh == 1) {
#pragma unroll
    for (int hb = 0; hb < 2; hb++)
#pragma unroll
      for (int r = 0; r < 16; r++) {
        const int hd = hb * 32 + (r & 3) + 8 * (r >> 2) + 4 * hi;
        sh.m.O[qg][hd][l31] = o[hb][r];
      }
    if (hi == 0) sh.m.L[qg][l31] = l;
  }
  __syncthreads();
  if (kvh == 0) {
#pragma unroll
    for (int hb = 0; hb < 2; hb++)
#pragma unroll
      for (int r = 0; r < 16; r++) {
        const int hd = hb * 32 + (r & 3) + 8 * (r >> 2) + 4 * hi;
        o[hb][r] += sh.m.O[qg][hd][l31];
      }
    l += sh.m.L[qg][l31];
    const float inv = 1.0f / l;
    __bf16* Ow = Og + (((size_t)b * Ss + qw) * Hh + h) * HD;
#pragma unroll
    for (int hb = 0; hb < 2; hb++)
#pragma unroll
      for (int g = 0; g < 4; g++) {
        const int hd = hb * 32 + g * 8 + 4 * hi;
        bf16x2 w0, w1;
        w0[0] = (__bf16)(o[hb][g * 4 + 0] * inv);
        w0[1] = (__bf16)(o[hb][g * 4 + 1] * inv);
        w1[0] = (__bf16)(o[hb][g * 4 + 2] * inv);
        w1[1] = (__bf16)(o[hb][g * 4 + 3] * inv);
        *(bf16x2*)(Ow + hd) = w0;
        *(bf16x2*)(Ow + hd + 2) = w1;
      }
  }
}

// ---------------------------------------------------------------------------
extern "C" void kernel_launch(void* const* d_in, const int* in_sizes, int n_in,
                              void* d_out, int out_size, void* d_ws,
                              size_t ws_size, hipStream_t stream) {
  if (ws_size < WS_NEED) return;

  __bf16* ws = (__bf16*)d_ws;
  const __bf16* hsC = ws + CAN_HS;
  const __bf16* WqC = ws + CAN_WQ;
  const __bf16* bqC = ws + CAN_BQ;
  const __bf16* WkC = ws + CAN_WK;
  const __bf16* bkC = ws + CAN_BK;
  const __bf16* WvC = ws + CAN_WV;
  const __bf16* bvC = ws + CAN_BV;
  const __bf16* WoC = ws + CAN_WO;
  const __bf16* boC = ws + CAN_BO;
  __bf16* Q = ws + CAN_END;
  __bf16* K = Q + TSZ;
  __bf16* V = K + TSZ;  // transposed layout [B,H,HD,S]
  __bf16* AW = V + TSZ;
  float* out = (float*)d_out;
  // bf16 mask (pre-scaled by log2e) lives in d_out until out-proj overwrites
  // it: B*S*S bf16 = 16.78MB = B*S*D fp32 exactly.
  __bf16* Mbf = (__bf16*)d_out;

  canon_kernel<<<2048, 256, 0, stream>>>(
      (const float*)d_in[0], (const float*)d_in[2], (const float*)d_in[3],
      (const float*)d_in[4], (const float*)d_in[5], (const float*)d_in[6],
      (const float*)d_in[7], (const float*)d_in[8], (const float*)d_in[9], ws);
  gemm_bt<0, __bf16><<<dim3(32, 32), 256, 0, stream>>>(
      hsC, WqC, WkC, WvC, bqC, bkC, bvC, Q, K, V, (const float*)d_in[1], Mbf);
  attn_fused<<<dim3(1024), 256, 0, stream>>>(Q, K, V, Mbf, AW);
  gemm_bt<1, float><<<dim3(32, 16), 256, 0, stream>>>(
      AW, WoC, WoC, WoC, boC, boC, boC, out, out, out, nullptr, nullptr);
}